// Round 9
// baseline (153.005 us; speedup 1.0000x reference)
//
#include <hip/hip_runtime.h>
#include <math.h>

#define NB 16
#define CF 64
#define LL 16384
#define GG 8
#define NH 2
#define CHN 64
#define NCH 256
#define NGRP 16

static constexpr size_t OFF_GT = 0;
static constexpr size_t OFF_U2 = OFF_GT + (size_t)NB*LL*GG;
static constexpr size_t OFF_AC = OFF_U2 + (size_t)NB*NCH*256;
static constexpr size_t OFF_PH = OFF_AC + (size_t)NB*NCH*NH;
static constexpr size_t OFF_CP = OFF_PH + (size_t)NB*NCH*256;
static constexpr size_t OFF_UG = OFF_CP + (size_t)NB*NCH*NH;
static constexpr size_t OFF_AG = OFF_UG + (size_t)NB*NGRP*256;
static constexpr size_t OFF_GH = OFF_AG + (size_t)NB*NGRP*NH;
static constexpr size_t OFF_G2 = OFF_GH + (size_t)NB*NGRP*256;
static constexpr size_t WS_FLOATS = OFF_G2 + (size_t)NB*LL*GG;

typedef float f32x4 __attribute__((ext_vector_type(4)));
typedef short bf16x8 __attribute__((ext_vector_type(8)));

__device__ __forceinline__ float siluf(float v){ return v / (1.f + __expf(-v)); }
__device__ __forceinline__ float softplusf(float v){ return v > 20.f ? v : log1pf(__expf(v)); }

__device__ __forceinline__ unsigned short f2bf(float f){
    unsigned int u = __float_as_uint(f);
    u += 0x7fffu + ((u >> 16) & 1u);
    return (unsigned short)(u >> 16);
}
__device__ __forceinline__ float bf2f(unsigned short s){
    return __uint_as_float(((unsigned int)s) << 16);
}
__device__ __forceinline__ unsigned int pack2bf(float lo, float hi){
    return (unsigned int)f2bf(lo) | ((unsigned int)f2bf(hi) << 16);
}
__device__ __forceinline__ unsigned int packtr(float lo, float hi){   // truncating pack
    return (__float_as_uint(hi) & 0xffff0000u) | (__float_as_uint(lo) >> 16);
}

__device__ __forceinline__ void load8(float* d, const float* p){
    float4 a = ((const float4*)p)[0];
    float4 b = ((const float4*)p)[1];
    d[0]=a.x; d[1]=a.y; d[2]=a.z; d[3]=a.w;
    d[4]=b.x; d[5]=b.y; d[6]=b.z; d[7]=b.w;
}

// K1a: tokenize x -> gt.  1024 blocks x 64 threads, 4 l per thread.
__global__ __launch_bounds__(64) void k1a_tok(
    const float* __restrict__ x, const float* __restrict__ tok_w,
    const float* __restrict__ tok_b, float* __restrict__ gtw)
{
    __shared__ float s_tok[GG*CF];
    int tid = threadIdx.x;
    int b  = blockIdx.x >> 6;
    int ck = blockIdx.x & 63;
    int l0 = (ck << 8) + (tid << 2);
    for (int i = tid; i < GG*CF; i += 64) s_tok[i] = tok_w[i];
    __syncthreads();
    float acc[4][GG];
    #pragma unroll
    for (int r = 0; r < 4; ++r)
        #pragma unroll
        for (int g = 0; g < GG; ++g) acc[r][g] = tok_b[g];
    const float* xb = x + (size_t)b*CF*LL + l0;
    #pragma unroll 8
    for (int c = 0; c < CF; ++c) {
        float4 xv = *(const float4*)(xb + (size_t)c*LL);
        float xa[4] = {xv.x, xv.y, xv.z, xv.w};
        #pragma unroll
        for (int g = 0; g < GG; ++g) {
            float w = s_tok[g*CF + c];
            #pragma unroll
            for (int r = 0; r < 4; ++r) acc[r][g] = fmaf(xa[r], w, acc[r][g]);
        }
    }
    float* gp = gtw + ((size_t)b*LL + l0)*GG;
    #pragma unroll
    for (int r = 0; r < 4; ++r) {
        ((float4*)gp)[r*2+0] = make_float4(acc[r][0],acc[r][1],acc[r][2],acc[r][3]);
        ((float4*)gp)[r*2+1] = make_float4(acc[r][4],acc[r][5],acc[r][6],acc[r][7]);
    }
}

// K2a: chunk end-state. Two-phase staging (pre-conv once), transpose phase, 2 MFMAs.
__global__ __launch_bounds__(256) void k2a_state(
    const float* __restrict__ gtw,
    const float* __restrict__ ipw, const float* __restrict__ ipb,
    const float* __restrict__ cw, const float* __restrict__ cb,
    const float* __restrict__ A_log, const float* __restrict__ dt_bias,
    float* __restrict__ U2w, float* __restrict__ Acw)
{
    __shared__ float s_pre[32*68];                      // pre-conv [ch][slot]
    __shared__ float s_xf[64*17];
    __shared__ float s_bf[64*17];
    __shared__ __align__(16) unsigned short WXbf[16*72];
    __shared__ __align__(16) unsigned short BTbf[16*72];
    __shared__ float s_dt[64][2], s_nda[64][2], s_w[64][2];
    __shared__ float s_ipw[256], s_ipb2[32], s_cw2[96], s_cb2[32], s_wdt[16];

    int tid = threadIdx.x;
    int b = blockIdx.x >> 8, c = blockIdx.x & 255;
    s_ipw[tid] = ipw[128 + tid];
    if (tid < 32) { s_ipb2[tid] = ipb[16 + tid]; s_cb2[tid] = cb[tid]; }
    else if (tid >= 64 && tid < 160) s_cw2[tid - 64] = cw[tid - 64];
    else if (tid >= 224 && tid < 240) s_wdt[tid - 224] = ipw[512 + (tid - 224)];
    __syncthreads();                                    // B0

    float a0e = __expf(A_log[0]), a1e = __expf(A_log[1]);
    float dtb0 = dt_bias[0], dtb1 = dt_bias[1];
    float bdt0 = ipb[64], bdt1 = ipb[65];

    int r = tid >> 2, sub = tid & 3;
    int l = c*CHN + r;
    {   // P1: pre-conv in_proj once per row; halo rows by threads tid<8
        float g0[8];
        load8(g0, gtw + ((size_t)b*LL + l)*GG);
        #pragma unroll
        for (int k = 0; k < 8; ++k) {
            int ch = sub*8 + k;
            float acc = s_ipb2[ch];
            #pragma unroll
            for (int g = 0; g < 8; ++g) acc = fmaf(g0[g], s_ipw[ch*8+g], acc);
            s_pre[ch*68 + r + 2] = acc;
        }
        if (r < 2) {
            int lh = c*CHN - 1 - r, slot = 1 - r;
            if (lh >= 0) {
                float gh[8];
                load8(gh, gtw + ((size_t)b*LL + lh)*GG);
                #pragma unroll
                for (int k = 0; k < 8; ++k) {
                    int ch = sub*8 + k;
                    float acc = s_ipb2[ch];
                    #pragma unroll
                    for (int g = 0; g < 8; ++g) acc = fmaf(gh[g], s_ipw[ch*8+g], acc);
                    s_pre[ch*68 + slot] = acc;
                }
            } else {
                #pragma unroll
                for (int k = 0; k < 8; ++k) s_pre[(sub*8+k)*68 + slot] = 0.f;
            }
        }
        if (sub == 0) {
            float d0 = bdt0, d1 = bdt1;
            #pragma unroll
            for (int g = 0; g < 8; ++g) {
                d0 = fmaf(g0[g], s_wdt[g],   d0);
                d1 = fmaf(g0[g], s_wdt[8+g], d1);
            }
            float dt0 = softplusf(d0 + dtb0), dt1 = softplusf(d1 + dtb1);
            s_dt[r][0] = dt0; s_dt[r][1] = dt1;
            s_nda[r][0] = -dt0*a0e; s_nda[r][1] = -dt1*a1e;
        }
    }
    __syncthreads();                                    // B1

    {   // P2: conv + silu -> fp32 x / B tiles
        #pragma unroll
        for (int k = 0; k < 8; ++k) {
            int ch = sub*8 + k;
            float p0 = s_pre[ch*68 + r];
            float p1 = s_pre[ch*68 + r + 1];
            float p2 = s_pre[ch*68 + r + 2];
            float a = s_cb2[ch];
            a = fmaf(p0, s_cw2[ch*3+0], a);
            a = fmaf(p1, s_cw2[ch*3+1], a);
            a = fmaf(p2, s_cw2[ch*3+2], a);
            float v = siluf(a);
            if (ch < 16) s_xf[r*17 + ch] = v;
            else         s_bf[r*17 + (ch-16)] = v;
        }
    }
    if (tid < 64) {   // cumsum + weights
        int rr = tid;
        float v0 = s_nda[rr][0], v1 = s_nda[rr][1];
        #pragma unroll
        for (int off = 1; off < 64; off <<= 1) {
            float t0 = __shfl_up(v0, off);
            float t1 = __shfl_up(v1, off);
            if (rr >= off) { v0 += t0; v1 += t1; }
        }
        float f0 = __shfl(v0, 63), f1 = __shfl(v1, 63);
        s_w[rr][0] = __expf(f0 - v0) * s_dt[rr][0];
        s_w[rr][1] = __expf(f1 - v1) * s_dt[rr][1];
        if (rr == 63)
            *(float2*)(Acw + ((size_t)b*NCH + c)*2) = make_float2(__expf(f0), __expf(f1));
    }
    __syncthreads();                                    // B2

    {   // P3: transposes -> bf16 (dword packed, b128 stores)
        int half = tid >> 7;
        int t2 = tid & 127;
        int p = t2 & 15, seg = t2 >> 4;
        unsigned int wd[4];
        if (half == 0) {
            #pragma unroll
            for (int j = 0; j < 4; ++j) {
                int s0 = seg*8 + 2*j, s1 = s0 + 1;
                float a0 = s_xf[s0*17 + p] * s_w[s0][p>>3];
                float a1 = s_xf[s1*17 + p] * s_w[s1][p>>3];
                wd[j] = pack2bf(a0, a1);
            }
            *(uint4*)&WXbf[p*72 + seg*8] = make_uint4(wd[0],wd[1],wd[2],wd[3]);
        } else {
            #pragma unroll
            for (int j = 0; j < 4; ++j) {
                int s0 = seg*8 + 2*j, s1 = s0 + 1;
                wd[j] = pack2bf(s_bf[s0*17 + p], s_bf[s1*17 + p]);
            }
            *(uint4*)&BTbf[p*72 + seg*8] = make_uint4(wd[0],wd[1],wd[2],wd[3]);
        }
    }
    __syncthreads();                                    // B3

    if (tid < 64) {
        int ar = tid & 15, kb = tid >> 4;
        f32x4 acc = {0.f, 0.f, 0.f, 0.f};
        #pragma unroll
        for (int kk = 0; kk < 2; ++kk) {
            bf16x8 aw = *(const bf16x8*)&WXbf[ar*72 + kk*32 + kb*8];
            bf16x8 bb = *(const bf16x8*)&BTbf[ar*72 + kk*32 + kb*8];
            acc = __builtin_amdgcn_mfma_f32_16x16x32_bf16(aw, bb, acc, 0, 0, 0);
        }
        #pragma unroll
        for (int rg = 0; rg < 4; ++rg)
            U2w[(((size_t)b*NCH + c) << 8) + (kb*4+rg)*16 + ar] = acc[rg];
    }
}

// K4c1: scan 16 chunks within each group (states preloaded).
__global__ void k4c1(const float* __restrict__ U2w, const float* __restrict__ Acw,
                     float* __restrict__ phw, float* __restrict__ cpw,
                     float* __restrict__ Ugw, float* __restrict__ Agw)
{
    int b = blockIdx.x >> 4, grp = blockIdx.x & 15;
    int e = threadIdx.x, he = e >> 7;
    size_t base = (size_t)b*NCH + grp*16;
    float u[16], A[16];
    #pragma unroll
    for (int j = 0; j < 16; ++j) u[j] = U2w[((base + j) << 8) + e];
    #pragma unroll
    for (int j = 0; j < 16; ++j) A[j] = Acw[(base + j)*2 + he];
    float h = 0.f, cp = 1.f;
    #pragma unroll
    for (int j = 0; j < 16; ++j) {
        phw[((base + j) << 8) + e] = h;
        if ((e & 127) == 0) cpw[(base + j)*2 + he] = cp;
        h = fmaf(A[j], h, u[j]);
        cp *= A[j];
    }
    Ugw[(((size_t)b*NGRP + grp) << 8) + e] = h;
    if ((e & 127) == 0) Agw[((size_t)b*NGRP + grp)*2 + he] = cp;
}

// K4c2: scan 16 group summaries.
__global__ void k4c2(const float* __restrict__ Ugw, const float* __restrict__ Agw,
                     float* __restrict__ ghw)
{
    int b = blockIdx.x, e = threadIdx.x, he = e >> 7;
    float u[NGRP], ag[NGRP];
    #pragma unroll
    for (int g = 0; g < NGRP; ++g) {
        u[g]  = Ugw[(((size_t)b*NGRP + g) << 8) + e];
        ag[g] = Agw[((size_t)b*NGRP + g)*2 + he];
    }
    float h = 0.f;
    #pragma unroll
    for (int g = 0; g < NGRP; ++g) {
        ghw[(((size_t)b*NGRP + g) << 8) + e] = h;
        h = fmaf(ag[g], h, u[g]);
    }
}

struct MMp {
    unsigned short M[64*80];       // M~, stride 80 (conflict-spread, 16B-aligned rows)
    unsigned short Cp0[64*16];
    unsigned short Cp1[64*16];
};
union SharedU {
    float pre[48*68];              // 13056 B (staging phase)
    MMp m;                         // 14336 B (SSD phase)
};

// K2b: full SSD + hin correction + epilogue -> g2.
__global__ __launch_bounds__(256) void k2b_fused(
    const float* __restrict__ gtw,
    const float* __restrict__ ipw, const float* __restrict__ ipb,
    const float* __restrict__ cw, const float* __restrict__ cb,
    const float* __restrict__ A_log, const float* __restrict__ dt_bias,
    const float* __restrict__ Dv, const float* __restrict__ norm_w,
    const float* __restrict__ out_w, const float* __restrict__ out_b,
    const float* __restrict__ phw, const float* __restrict__ cpw,
    const float* __restrict__ ghw,
    float* __restrict__ g2w)
{
    __shared__ __align__(16) unsigned short Cbf[64*40];   // C rows (yb overlays later)
    __shared__ __align__(16) unsigned short Bbf[64*40];
    __shared__ __align__(16) unsigned short XTbf[16*72];
    __shared__ float s_xf[64*17];                          // x fp32 [r][p], stride 17
    __shared__ SharedU su;
    __shared__ float s_hin[256];
    __shared__ float s_dt[64][2], s_nda[64][2], s_la[64][2];
    __shared__ float s_eti[2][64], s_etd[2][64], s_esc[2][4][4];
    __shared__ float s_ipw[384], s_ipb2[48], s_cw2[144], s_cb2[48], s_wdt[16];
    __shared__ float s_zw[128], s_ow[128], s_zb[16], s_nw[16], s_ob[8];

    int tid = threadIdx.x;
    int b = blockIdx.x >> 8, c = blockIdx.x & 255;

    {   // hin reconstruction
        int grp = c >> 4;
        float gh  = ghw[(((size_t)b*NGRP + grp) << 8) + tid];
        float cpv = cpw[((size_t)b*NCH + c)*2 + (tid >> 7)];
        float phv = phw[(((size_t)b*NCH + c) << 8) + tid];
        s_hin[tid] = fmaf(cpv, gh, phv);
    }
    for (int i = tid; i < 384; i += 256) s_ipw[i] = ipw[128 + i];
    if (tid < 128) s_zw[tid] = ipw[tid];
    else s_ow[tid-128] = out_w[tid-128];
    if (tid < 48) { s_ipb2[tid] = ipb[16 + tid]; s_cb2[tid] = cb[tid]; }
    else if (tid >= 64 && tid < 208) s_cw2[tid - 64] = cw[tid - 64];
    else if (tid >= 224 && tid < 240) s_wdt[tid - 224] = ipw[512 + (tid - 224)];
    if (tid < 16) { s_zb[tid] = ipb[tid]; s_nw[tid] = norm_w[tid]; }
    else if (tid < 24) s_ob[tid-16] = out_b[tid-16];
    __syncthreads();                                      // B0

    float a0e = __expf(A_log[0]), a1e = __expf(A_log[1]);
    float dtb0 = dt_bias[0], dtb1 = dt_bias[1];
    float bdt0 = ipb[64], bdt1 = ipb[65];
    float D0 = Dv[0], D1 = Dv[1];

    int r = tid >> 2, sub = tid & 3;
    int l = c*CHN + r;
    float g0[8];                                          // kept live to epilogue
    {   // P1: pre-conv in_proj once per row (12 ch per thread); halo by tid<8
        load8(g0, gtw + ((size_t)b*LL + l)*GG);
        #pragma unroll
        for (int k = 0; k < 12; ++k) {
            int ch = sub*12 + k;
            float acc = s_ipb2[ch];
            #pragma unroll
            for (int g = 0; g < 8; ++g) acc = fmaf(g0[g], s_ipw[ch*8+g], acc);
            su.pre[ch*68 + r + 2] = acc;
        }
        if (r < 2) {
            int lh = c*CHN - 1 - r, slot = 1 - r;
            if (lh >= 0) {
                float gh[8];
                load8(gh, gtw + ((size_t)b*LL + lh)*GG);
                #pragma unroll
                for (int k = 0; k < 12; ++k) {
                    int ch = sub*12 + k;
                    float acc = s_ipb2[ch];
                    #pragma unroll
                    for (int g = 0; g < 8; ++g) acc = fmaf(gh[g], s_ipw[ch*8+g], acc);
                    su.pre[ch*68 + slot] = acc;
                }
            } else {
                #pragma unroll
                for (int k = 0; k < 12; ++k) su.pre[(sub*12+k)*68 + slot] = 0.f;
            }
        }
        if (sub == 0) {
            float d0 = bdt0, d1 = bdt1;
            #pragma unroll
            for (int g = 0; g < 8; ++g) {
                d0 = fmaf(g0[g], s_wdt[g],   d0);
                d1 = fmaf(g0[g], s_wdt[8+g], d1);
            }
            float dt0 = softplusf(d0 + dtb0), dt1 = softplusf(d1 + dtb1);
            s_dt[r][0] = dt0; s_dt[r][1] = dt1;
            s_nda[r][0] = -dt0*a0e; s_nda[r][1] = -dt1*a1e;
        }
    }
    __syncthreads();                                      // B1

    {   // P2: conv + silu -> x fp32, B/C bf16 (dword packed)
        float vals[12];
        #pragma unroll
        for (int k = 0; k < 12; ++k) {
            int ch = sub*12 + k;
            float p0 = su.pre[ch*68 + r];
            float p1 = su.pre[ch*68 + r + 1];
            float p2 = su.pre[ch*68 + r + 2];
            float a = s_cb2[ch];
            a = fmaf(p0, s_cw2[ch*3+0], a);
            a = fmaf(p1, s_cw2[ch*3+1], a);
            a = fmaf(p2, s_cw2[ch*3+2], a);
            vals[k] = siluf(a);
        }
        if (sub == 0) {
            #pragma unroll
            for (int k = 0; k < 12; ++k) s_xf[r*17 + k] = vals[k];
        } else if (sub == 1) {
            #pragma unroll
            for (int k = 0; k < 4; ++k) s_xf[r*17 + 12 + k] = vals[k];
            unsigned int* bp = (unsigned int*)&Bbf[r*40];
            #pragma unroll
            for (int j = 0; j < 4; ++j) bp[j] = pack2bf(vals[4+2*j], vals[5+2*j]);
        } else if (sub == 2) {
            unsigned int* bp = (unsigned int*)&Bbf[r*40 + 8];
            #pragma unroll
            for (int j = 0; j < 4; ++j) bp[j] = pack2bf(vals[2*j], vals[1+2*j]);
            unsigned int* cp = (unsigned int*)&Cbf[r*40];
            #pragma unroll
            for (int j = 0; j < 2; ++j) cp[j] = pack2bf(vals[8+2*j], vals[9+2*j]);
        } else {
            unsigned int* cp = (unsigned int*)&Cbf[r*40 + 4];
            #pragma unroll
            for (int j = 0; j < 6; ++j) cp[j] = pack2bf(vals[2*j], vals[1+2*j]);
        }
        unsigned int* cz = (unsigned int*)&Cbf[r*40 + 16];
        unsigned int* bz = (unsigned int*)&Bbf[r*40 + 16];
        cz[sub*2+0] = 0u; cz[sub*2+1] = 0u;
        bz[sub*2+0] = 0u; bz[sub*2+1] = 0u;
    }
    if (tid < 64) {   // cumsum -> la
        int rr = tid;
        float v0 = s_nda[rr][0], v1 = s_nda[rr][1];
        #pragma unroll
        for (int off = 1; off < 64; off <<= 1) {
            float t0 = __shfl_up(v0, off);
            float t1 = __shfl_up(v1, off);
            if (rr >= off) { v0 += t0; v1 += t1; }
        }
        s_la[rr][0] = v0; s_la[rr][1] = v1;
    }
    __syncthreads();                                      // B2

    int lane = tid & 63, wv = tid >> 6;
    int ar = lane & 15, kb = lane >> 4;
    int trow = wv*16 + kb*4;

    // G = C.B^T (per-wave registers, causal tiles only)
    f32x4 gT[4];
    {
        bf16x8 aC = *(const bf16x8*)&Cbf[(wv*16 + ar)*40 + kb*8];
        #pragma unroll
        for (int ss = 0; ss < 4; ++ss) {
            f32x4 g = {0.f, 0.f, 0.f, 0.f};
            if (ss <= wv) {
                bf16x8 bB = *(const bf16x8*)&Bbf[(ss*16 + ar)*40 + kb*8];
                g = __builtin_amdgcn_mfma_f32_16x16x32_bf16(aC, bB, g, 0, 0, 0);
            }
            gT[ss] = g;
        }
    }
    // XT transpose (tid<128) || exp tables (tid>=128)
    if (tid < 128) {
        int p = tid & 15, seg = tid >> 4;
        unsigned int wd[4];
        #pragma unroll
        for (int j = 0; j < 4; ++j) {
            int s0 = seg*8 + 2*j, s1 = s0 + 1;
            wd[j] = pack2bf(s_xf[s0*17 + p], s_xf[s1*17 + p]);
        }
        *(uint4*)&XTbf[p*72 + seg*8] = make_uint4(wd[0],wd[1],wd[2],wd[3]);
    } else {
        int i = tid - 128;
        int h = i >> 6, s = i & 63;
        int anc = s & ~15;
        float d = s_la[anc][h] - s_la[s][h];
        float et = __expf(d);
        s_eti[h][s] = __expf(-d);
        s_etd[h][s] = et * s_dt[s][h];
        if (i < 32) {
            int h2 = i >> 4, wt = (i >> 2) & 3, ws = i & 3;
            s_esc[h2][wt][ws] = (wt >= ws) ? __expf(s_la[wt*16][h2] - s_la[ws*16][h2]) : 0.f;
        }
    }
    {   // C' = exp(la)*C, both heads
        int h = tid >> 7;
        int rr = (tid & 127) >> 1;
        int nh = (tid & 1) * 8;
        float sc = __expf(s_la[rr][h]);
        unsigned short* Cp = h ? su.m.Cp1 : su.m.Cp0;
        unsigned int* dst = (unsigned int*)&Cp[rr*16 + nh];
        #pragma unroll
        for (int j = 0; j < 4; ++j)
            dst[j] = pack2bf(sc * bf2f(Cbf[rr*40 + nh + j*2]),
                             sc * bf2f(Cbf[rr*40 + nh + j*2 + 1]));
    }
    __syncthreads();                                      // B3

    {   // M~ head0 build (table-driven, zero exp; trunc-packed dword stores)
        float rowf[4];
        #pragma unroll
        for (int rg = 0; rg < 4; ++rg) rowf[rg] = s_eti[0][trow+rg];
        #pragma unroll
        for (int ss = 0; ss < 4; ++ss) {
            int s = ss*16 + ar;
            if (ss > wv) {
                if (!(ar & 1)) {
                    #pragma unroll
                    for (int rg = 0; rg < 4; ++rg)
                        *(unsigned int*)&su.m.M[(trow+rg)*80 + ss*16 + ar] = 0u;
                }
                continue;
            }
            float colf = s_esc[0][wv][ss] * s_etd[0][s];
            #pragma unroll
            for (int rg = 0; rg < 4; ++rg) {
                float m = (s <= trow+rg) ? rowf[rg]*colf*gT[ss][rg] : 0.f;
                float mp = __shfl_xor(m, 1);
                if (!(ar & 1))
                    *(unsigned int*)&su.m.M[(trow+rg)*80 + ss*16 + ar] = packtr(m, mp);
            }
        }
    }
    __syncthreads();                                      // B4

    // Y head0 = M~.X + C'h0.hin0
    f32x4 acc0 = {0.f, 0.f, 0.f, 0.f};
    {
        int p = ar;
        #pragma unroll
        for (int kk = 0; kk < 2; ++kk) {
            bf16x8 am = *(const bf16x8*)&su.m.M[(wv*16 + ar)*80 + kk*32 + kb*8];
            bf16x8 bx = {0,0,0,0,0,0,0,0};
            if (p < 8) bx = *(const bf16x8*)&XTbf[p*72 + kk*32 + kb*8];
            acc0 = __builtin_amdgcn_mfma_f32_16x16x32_bf16(am, bx, acc0, 0, 0, 0);
        }
        bf16x8 aCp = {0,0,0,0,0,0,0,0};
        if (kb < 2) aCp = *(const bf16x8*)&su.m.Cp0[(wv*16 + ar)*16 + kb*8];
        bf16x8 bh = {0,0,0,0,0,0,0,0};
        if (kb < 2) {
            #pragma unroll
            for (int j = 0; j < 8; ++j)
                bh[j] = (short)f2bf(s_hin[0*128 + (ar&7)*16 + kb*8 + j]);
        }
        acc0 = __builtin_amdgcn_mfma_f32_16x16x32_bf16(aCp, bh, acc0, 0, 0, 0);
    }
    __syncthreads();                                      // B5

    {   // M~ head1 build
        float rowf[4];
        #pragma unroll
        for (int rg = 0; rg < 4; ++rg) rowf[rg] = s_eti[1][trow+rg];
        #pragma unroll
        for (int ss = 0; ss < 4; ++ss) {
            int s = ss*16 + ar;
            if (ss > wv) {
                if (!(ar & 1)) {
                    #pragma unroll
                    for (int rg = 0; rg < 4; ++rg)
                        *(unsigned int*)&su.m.M[(trow+rg)*80 + ss*16 + ar] = 0u;
                }
                continue;
            }
            float colf = s_esc[1][wv][ss] * s_etd[1][s];
            #pragma unroll
            for (int rg = 0; rg < 4; ++rg) {
                float m = (s <= trow+rg) ? rowf[rg]*colf*gT[ss][rg] : 0.f;
                float mp = __shfl_xor(m, 1);
                if (!(ar & 1))
                    *(unsigned int*)&su.m.M[(trow+rg)*80 + ss*16 + ar] = packtr(m, mp);
            }
        }
    }
    __syncthreads();                                      // B6

    // Y head1 + yb store (yb overlays Cbf, dead after B3)
    float* yb = (float*)Cbf;
    {
        int p = ar;
        f32x4 acc1 = {0.f, 0.f, 0.f, 0.f};
        #pragma unroll
        for (int kk = 0; kk < 2; ++kk) {
            bf16x8 am = *(const bf16x8*)&su.m.M[(wv*16 + ar)*80 + kk*32 + kb*8];
            bf16x8 bx = {0,0,0,0,0,0,0,0};
            if (p < 8) bx = *(const bf16x8*)&XTbf[(8 + p)*72 + kk*32 + kb*8];
            acc1 = __builtin_amdgcn_mfma_f32_16x16x32_bf16(am, bx, acc1, 0, 0, 0);
        }
        bf16x8 aCp = {0,0,0,0,0,0,0,0};
        if (kb < 2) aCp = *(const bf16x8*)&su.m.Cp1[(wv*16 + ar)*16 + kb*8];
        bf16x8 bh = {0,0,0,0,0,0,0,0};
        if (kb < 2) {
            #pragma unroll
            for (int j = 0; j < 8; ++j)
                bh[j] = (short)f2bf(s_hin[1*128 + (ar&7)*16 + kb*8 + j]);
        }
        acc1 = __builtin_amdgcn_mfma_f32_16x16x32_bf16(aCp, bh, acc1, 0, 0, 0);
        if (p < 8) {
            #pragma unroll
            for (int rg = 0; rg < 4; ++rg) {
                int t = trow + rg;
                yb[t*20 + p]     = fmaf(D0, s_xf[t*17 + p],     acc0[rg]);
                yb[t*20 + 8 + p] = fmaf(D1, s_xf[t*17 + 8 + p], acc1[rg]);
            }
        }
    }
    __syncthreads();                                      // B7

    {   // epilogue: silu gate, RMSNorm, out proj, residual (g0 retained from P1)
        int q = sub;
        float vv[4]; float ssq = 0.f;
        #pragma unroll
        for (int j = 0; j < 4; ++j) {
            int hp = q*4 + j;
            float zz = s_zb[hp];
            #pragma unroll
            for (int g = 0; g < 8; ++g) zz = fmaf(g0[g], s_zw[hp*8+g], zz);
            float y = yb[r*20 + hp];
            float w = y * siluf(zz);
            vv[j] = w; ssq = fmaf(w, w, ssq);
        }
        ssq += __shfl_xor(ssq, 1);
        ssq += __shfl_xor(ssq, 2);
        float rn = rsqrtf(ssq*(1.f/16.f) + 1e-5f);
        float o[8];
        #pragma unroll
        for (int g = 0; g < 8; ++g) o[g] = 0.f;
        #pragma unroll
        for (int j = 0; j < 4; ++j) {
            float wj = vv[j] * rn * s_nw[q*4+j];
            #pragma unroll
            for (int g = 0; g < 8; ++g) o[g] = fmaf(wj, s_ow[g*16 + q*4 + j], o[g]);
        }
        #pragma unroll
        for (int g = 0; g < 8; ++g) {
            o[g] += __shfl_xor(o[g], 1);
            o[g] += __shfl_xor(o[g], 2);
        }
        if (q == 0) {
            #pragma unroll
            for (int g = 0; g < 8; ++g) o[g] += s_ob[g] + g0[g];
            float* gp = g2w + ((size_t)b*LL + c*CHN + r)*GG;
            ((float4*)gp)[0] = make_float4(o[0],o[1],o[2],o[3]);
            ((float4*)gp)[1] = make_float4(o[4],o[5],o[6],o[7]);
        }
    }
}

// K5b: out = x + detok(g2) + detok_b.  1024 blocks x 64 threads.
__global__ __launch_bounds__(64) void k5b_detok(
    const float* __restrict__ x, const float* __restrict__ g2w,
    const float* __restrict__ dkw, const float* __restrict__ dkb,
    float* __restrict__ outp)
{
    __shared__ float s_dw[CF*GG];
    __shared__ float s_db[CF];
    int tid = threadIdx.x;
    int b  = blockIdx.x >> 6;
    int ck = blockIdx.x & 63;
    int l0 = (ck << 8) + (tid << 2);
    for (int i = tid; i < CF*GG; i += 64) s_dw[i] = dkw[i];
    s_db[tid] = dkb[tid];
    __syncthreads();
    float g2v[4][8];
    const float* gp = g2w + ((size_t)b*LL + l0)*GG;
    #pragma unroll
    for (int r = 0; r < 4; ++r) load8(g2v[r], gp + r*GG);
    const float* xb = x + (size_t)b*CF*LL + l0;
    float* ob = outp + (size_t)b*CF*LL + l0;
    #pragma unroll 4
    for (int c = 0; c < CF; ++c) {
        float4 xv = *(const float4*)(xb + (size_t)c*LL);
        float bias = s_db[c];
        float oa[4] = {xv.x+bias, xv.y+bias, xv.z+bias, xv.w+bias};
        #pragma unroll
        for (int g = 0; g < GG; ++g) {
            float w = s_dw[c*GG+g];
            #pragma unroll
            for (int r = 0; r < 4; ++r) oa[r] = fmaf(g2v[r][g], w, oa[r]);
        }
        *(float4*)(ob + (size_t)c*LL) = make_float4(oa[0],oa[1],oa[2],oa[3]);
    }
}

extern "C" void kernel_launch(void* const* d_in, const int* in_sizes, int n_in,
                              void* d_out, int out_size, void* d_ws, size_t ws_size,
                              hipStream_t stream) {
    const float* x       = (const float*)d_in[0];
    const float* tok_w   = (const float*)d_in[1];
    const float* tok_b   = (const float*)d_in[2];
    const float* detok_w = (const float*)d_in[3];
    const float* detok_b = (const float*)d_in[4];
    const float* ipw     = (const float*)d_in[5];
    const float* ipb     = (const float*)d_in[6];
    const float* cw      = (const float*)d_in[7];
    const float* cb      = (const float*)d_in[8];
    const float* A_log   = (const float*)d_in[9];
    const float* Dv      = (const float*)d_in[10];
    const float* dt_bias = (const float*)d_in[11];
    const float* norm_w  = (const float*)d_in[12];
    const float* out_w   = (const float*)d_in[13];
    const float* out_b   = (const float*)d_in[14];
    float* ws = (float*)d_ws;
    float* outp = (float*)d_out;

    if (ws_size < WS_FLOATS * sizeof(float)) return;

    k1a_tok<<<NB*64, 64, 0, stream>>>(x, tok_w, tok_b, ws+OFF_GT);
    k2a_state<<<NB*NCH, 256, 0, stream>>>(ws+OFF_GT, ipw, ipb, cw, cb,
        A_log, dt_bias, ws+OFF_U2, ws+OFF_AC);
    k4c1<<<NB*NGRP, 256, 0, stream>>>(ws+OFF_U2, ws+OFF_AC,
        ws+OFF_PH, ws+OFF_CP, ws+OFF_UG, ws+OFF_AG);
    k4c2<<<NB, 256, 0, stream>>>(ws+OFF_UG, ws+OFF_AG, ws+OFF_GH);
    k2b_fused<<<NB*NCH, 256, 0, stream>>>(ws+OFF_GT, ipw, ipb, cw, cb,
        A_log, dt_bias, Dv, norm_w, out_w, out_b,
        ws+OFF_PH, ws+OFF_CP, ws+OFF_GH, ws+OFF_G2);
    k5b_detok<<<NB*64, 64, 0, stream>>>(x, ws+OFF_G2, detok_w, detok_b, outp);
}

// Round 10
// 131.592 us; speedup vs baseline: 1.1627x; 1.1627x over previous
//
#include <hip/hip_runtime.h>
#include <math.h>

#define NB 16
#define CF 64
#define LL 16384
#define GG 8
#define NH 2
#define CHN 64
#define NCH 256
#define NGRP 16

static constexpr size_t OFF_GT = 0;
static constexpr size_t OFF_U2 = OFF_GT + (size_t)NB*LL*GG;
static constexpr size_t OFF_AC = OFF_U2 + (size_t)NB*NCH*256;
static constexpr size_t OFF_PH = OFF_AC + (size_t)NB*NCH*NH;
static constexpr size_t OFF_CP = OFF_PH + (size_t)NB*NCH*256;
static constexpr size_t OFF_UG = OFF_CP + (size_t)NB*NCH*NH;
static constexpr size_t OFF_AG = OFF_UG + (size_t)NB*NGRP*256;
static constexpr size_t OFF_GH = OFF_AG + (size_t)NB*NGRP*NH;
static constexpr size_t OFF_G2 = OFF_GH + (size_t)NB*NGRP*256;
static constexpr size_t OFF_ST = OFF_G2 + (size_t)NB*LL*GG;
// per-chunk staged record: 1792 floats = XT[512] B[512] C[512] la[128] dt[128]
static constexpr size_t WS_FLOATS = OFF_ST + (size_t)NB*NCH*1792;

typedef float f32x4 __attribute__((ext_vector_type(4)));
typedef short bf16x8 __attribute__((ext_vector_type(8)));

__device__ __forceinline__ float siluf(float v){ return v / (1.f + __expf(-v)); }
__device__ __forceinline__ float softplusf(float v){ return v > 20.f ? v : log1pf(__expf(v)); }

__device__ __forceinline__ unsigned short f2bf(float f){
    unsigned int u = __float_as_uint(f);
    u += 0x7fffu + ((u >> 16) & 1u);
    return (unsigned short)(u >> 16);
}
__device__ __forceinline__ float bf2f(unsigned short s){
    return __uint_as_float(((unsigned int)s) << 16);
}
__device__ __forceinline__ unsigned int pack2bf(float lo, float hi){
    return (unsigned int)f2bf(lo) | ((unsigned int)f2bf(hi) << 16);
}
__device__ __forceinline__ unsigned int packtr(float lo, float hi){
    return (__float_as_uint(hi) & 0xffff0000u) | (__float_as_uint(lo) >> 16);
}

__device__ __forceinline__ void load8(float* d, const float* p){
    float4 a = ((const float4*)p)[0];
    float4 b = ((const float4*)p)[1];
    d[0]=a.x; d[1]=a.y; d[2]=a.z; d[3]=a.w;
    d[4]=b.x; d[5]=b.y; d[6]=b.z; d[7]=b.w;
}

// K1a: tokenize x -> gt.
__global__ __launch_bounds__(64) void k1a_tok(
    const float* __restrict__ x, const float* __restrict__ tok_w,
    const float* __restrict__ tok_b, float* __restrict__ gtw)
{
    __shared__ float s_tok[GG*CF];
    int tid = threadIdx.x;
    int b  = blockIdx.x >> 6;
    int ck = blockIdx.x & 63;
    int l0 = (ck << 8) + (tid << 2);
    for (int i = tid; i < GG*CF; i += 64) s_tok[i] = tok_w[i];
    __syncthreads();
    float acc[4][GG];
    #pragma unroll
    for (int r = 0; r < 4; ++r)
        #pragma unroll
        for (int g = 0; g < GG; ++g) acc[r][g] = tok_b[g];
    const float* xb = x + (size_t)b*CF*LL + l0;
    #pragma unroll 8
    for (int c = 0; c < CF; ++c) {
        float4 xv = *(const float4*)(xb + (size_t)c*LL);
        float xa[4] = {xv.x, xv.y, xv.z, xv.w};
        #pragma unroll
        for (int g = 0; g < GG; ++g) {
            float w = s_tok[g*CF + c];
            #pragma unroll
            for (int r = 0; r < 4; ++r) acc[r][g] = fmaf(xa[r], w, acc[r][g]);
        }
    }
    float* gp = gtw + ((size_t)b*LL + l0)*GG;
    #pragma unroll
    for (int r = 0; r < 4; ++r) {
        ((float4*)gp)[r*2+0] = make_float4(acc[r][0],acc[r][1],acc[r][2],acc[r][3]);
        ((float4*)gp)[r*2+1] = make_float4(acc[r][4],acc[r][5],acc[r][6],acc[r][7]);
    }
}

// K2a: stage (in_proj+conv+silu once) -> persist bf16 tiles + la/dt; chunk end-state MFMA.
__global__ __launch_bounds__(256) void k2a_state(
    const float* __restrict__ gtw,
    const float* __restrict__ ipw, const float* __restrict__ ipb,
    const float* __restrict__ cw, const float* __restrict__ cb,
    const float* __restrict__ A_log, const float* __restrict__ dt_bias,
    float* __restrict__ stw,
    float* __restrict__ U2w, float* __restrict__ Acw)
{
    __shared__ float s_pre[48*68];
    __shared__ float s_xf[64*17], s_bf[64*17], s_cf[64*17];
    __shared__ __align__(16) unsigned short WXbf[16*72];
    __shared__ __align__(16) unsigned short BTbf[16*72];
    __shared__ float s_dt[64][2], s_nda[64][2], s_w[64][2];
    __shared__ float s_ipw[384], s_ipb2[48], s_cw2[144], s_cb2[48], s_wdt[16];

    int tid = threadIdx.x;
    int b = blockIdx.x >> 8, c = blockIdx.x & 255;
    float* stp = stw + ((size_t)(b*NCH + c))*1792;
    for (int i = tid; i < 384; i += 256) s_ipw[i] = ipw[128 + i];
    if (tid < 48) { s_ipb2[tid] = ipb[16 + tid]; s_cb2[tid] = cb[tid]; }
    else if (tid >= 64 && tid < 208) s_cw2[tid - 64] = cw[tid - 64];
    else if (tid >= 224 && tid < 240) s_wdt[tid - 224] = ipw[512 + (tid - 224)];
    __syncthreads();                                    // B0

    float a0e = __expf(A_log[0]), a1e = __expf(A_log[1]);
    float dtb0 = dt_bias[0], dtb1 = dt_bias[1];
    float bdt0 = ipb[64], bdt1 = ipb[65];

    int r = tid >> 2, sub = tid & 3;
    int l = c*CHN + r;
    {   // P1: pre-conv in_proj ONCE per row (12 ch/thread); halo rows by r<2 threads
        float g0[8];
        load8(g0, gtw + ((size_t)b*LL + l)*GG);
        #pragma unroll
        for (int k = 0; k < 12; ++k) {
            int ch = sub*12 + k;
            float acc = s_ipb2[ch];
            #pragma unroll
            for (int g = 0; g < 8; ++g) acc = fmaf(g0[g], s_ipw[ch*8+g], acc);
            s_pre[ch*68 + r + 2] = acc;
        }
        if (r < 2) {
            int lh = c*CHN - 1 - r, slot = 1 - r;
            if (lh >= 0) {
                float gh[8];
                load8(gh, gtw + ((size_t)b*LL + lh)*GG);
                #pragma unroll
                for (int k = 0; k < 12; ++k) {
                    int ch = sub*12 + k;
                    float acc = s_ipb2[ch];
                    #pragma unroll
                    for (int g = 0; g < 8; ++g) acc = fmaf(gh[g], s_ipw[ch*8+g], acc);
                    s_pre[ch*68 + slot] = acc;
                }
            } else {
                #pragma unroll
                for (int k = 0; k < 12; ++k) s_pre[(sub*12+k)*68 + slot] = 0.f;
            }
        }
        if (sub == 0) {
            float d0 = bdt0, d1 = bdt1;
            #pragma unroll
            for (int g = 0; g < 8; ++g) {
                d0 = fmaf(g0[g], s_wdt[g],   d0);
                d1 = fmaf(g0[g], s_wdt[8+g], d1);
            }
            float dt0 = softplusf(d0 + dtb0), dt1 = softplusf(d1 + dtb1);
            s_dt[r][0] = dt0; s_dt[r][1] = dt1;
            s_nda[r][0] = -dt0*a0e; s_nda[r][1] = -dt1*a1e;
        }
    }
    __syncthreads();                                    // B1

    {   // P2: conv + silu -> fp32 tiles
        #pragma unroll
        for (int k = 0; k < 12; ++k) {
            int ch = sub*12 + k;
            float p0 = s_pre[ch*68 + r];
            float p1 = s_pre[ch*68 + r + 1];
            float p2 = s_pre[ch*68 + r + 2];
            float a = s_cb2[ch];
            a = fmaf(p0, s_cw2[ch*3+0], a);
            a = fmaf(p1, s_cw2[ch*3+1], a);
            a = fmaf(p2, s_cw2[ch*3+2], a);
            float v = siluf(a);
            if (ch < 16)      s_xf[r*17 + ch] = v;
            else if (ch < 32) s_bf[r*17 + (ch-16)] = v;
            else              s_cf[r*17 + (ch-32)] = v;
        }
    }
    if (tid < 64) {   // cumsum + weights + la/dt persist + Ac
        int rr = tid;
        float v0 = s_nda[rr][0], v1 = s_nda[rr][1];
        #pragma unroll
        for (int off = 1; off < 64; off <<= 1) {
            float t0 = __shfl_up(v0, off);
            float t1 = __shfl_up(v1, off);
            if (rr >= off) { v0 += t0; v1 += t1; }
        }
        float f0 = __shfl(v0, 63), f1 = __shfl(v1, 63);
        s_w[rr][0] = __expf(f0 - v0) * s_dt[rr][0];
        s_w[rr][1] = __expf(f1 - v1) * s_dt[rr][1];
        stp[1536 + rr*2 + 0] = v0;
        stp[1536 + rr*2 + 1] = v1;
        stp[1664 + rr*2 + 0] = s_dt[rr][0];
        stp[1664 + rr*2 + 1] = s_dt[rr][1];
        if (rr == 63)
            *(float2*)(Acw + ((size_t)b*NCH + c)*2) = make_float2(__expf(f0), __expf(f1));
    }
    __syncthreads();                                    // B2

    {   // P3: transposes + persists (dword packed)
        unsigned int* stX = (unsigned int*)stp;
        unsigned int* stB = (unsigned int*)(stp + 512);
        unsigned int* stC = (unsigned int*)(stp + 1024);
        int half = tid >> 7;
        int t2 = tid & 127;
        int p = t2 & 15, seg = t2 >> 4;
        if (half == 0) {
            unsigned int wdW[4], wdX[4];
            #pragma unroll
            for (int j = 0; j < 4; ++j) {
                int s0 = seg*8 + 2*j, s1 = s0 + 1;
                float x0 = s_xf[s0*17 + p], x1 = s_xf[s1*17 + p];
                wdX[j] = pack2bf(x0, x1);
                wdW[j] = pack2bf(x0 * s_w[s0][p>>3], x1 * s_w[s1][p>>3]);
            }
            *(uint4*)&WXbf[p*72 + seg*8] = make_uint4(wdW[0],wdW[1],wdW[2],wdW[3]);
            *(uint4*)&stX[p*32 + seg*4]  = make_uint4(wdX[0],wdX[1],wdX[2],wdX[3]);
        } else {
            unsigned int wd[4];
            #pragma unroll
            for (int j = 0; j < 4; ++j) {
                int s0 = seg*8 + 2*j, s1 = s0 + 1;
                wd[j] = pack2bf(s_bf[s0*17 + p], s_bf[s1*17 + p]);
            }
            *(uint4*)&BTbf[p*72 + seg*8] = make_uint4(wd[0],wd[1],wd[2],wd[3]);
            int r2 = t2 >> 1, hf = t2 & 1;
            unsigned int wb[4], wc[4];
            #pragma unroll
            for (int j = 0; j < 4; ++j) {
                int c0 = hf*8 + 2*j;
                wb[j] = pack2bf(s_bf[r2*17 + c0], s_bf[r2*17 + c0 + 1]);
                wc[j] = pack2bf(s_cf[r2*17 + c0], s_cf[r2*17 + c0 + 1]);
            }
            *(uint4*)&stB[r2*8 + hf*4] = make_uint4(wb[0],wb[1],wb[2],wb[3]);
            *(uint4*)&stC[r2*8 + hf*4] = make_uint4(wc[0],wc[1],wc[2],wc[3]);
        }
    }
    __syncthreads();                                    // B3

    if (tid < 64) {
        int ar = tid & 15, kb = tid >> 4;
        f32x4 acc = {0.f, 0.f, 0.f, 0.f};
        #pragma unroll
        for (int kk = 0; kk < 2; ++kk) {
            bf16x8 aw = *(const bf16x8*)&WXbf[ar*72 + kk*32 + kb*8];
            bf16x8 bb = *(const bf16x8*)&BTbf[ar*72 + kk*32 + kb*8];
            acc = __builtin_amdgcn_mfma_f32_16x16x32_bf16(aw, bb, acc, 0, 0, 0);
        }
        #pragma unroll
        for (int rg = 0; rg < 4; ++rg)
            U2w[(((size_t)b*NCH + c) << 8) + (kb*4+rg)*16 + ar] = acc[rg];
    }
}

// K4c1: scan 16 chunks within each group.
__global__ void k4c1(const float* __restrict__ U2w, const float* __restrict__ Acw,
                     float* __restrict__ phw, float* __restrict__ cpw,
                     float* __restrict__ Ugw, float* __restrict__ Agw)
{
    int b = blockIdx.x >> 4, grp = blockIdx.x & 15;
    int e = threadIdx.x, he = e >> 7;
    size_t base = (size_t)b*NCH + grp*16;
    float u[16], A[16];
    #pragma unroll
    for (int j = 0; j < 16; ++j) u[j] = U2w[((base + j) << 8) + e];
    #pragma unroll
    for (int j = 0; j < 16; ++j) A[j] = Acw[(base + j)*2 + he];
    float h = 0.f, cp = 1.f;
    #pragma unroll
    for (int j = 0; j < 16; ++j) {
        phw[((base + j) << 8) + e] = h;
        if ((e & 127) == 0) cpw[(base + j)*2 + he] = cp;
        h = fmaf(A[j], h, u[j]);
        cp *= A[j];
    }
    Ugw[(((size_t)b*NGRP + grp) << 8) + e] = h;
    if ((e & 127) == 0) Agw[((size_t)b*NGRP + grp)*2 + he] = cp;
}

// K4c2: scan 16 group summaries.
__global__ void k4c2(const float* __restrict__ Ugw, const float* __restrict__ Agw,
                     float* __restrict__ ghw)
{
    int b = blockIdx.x, e = threadIdx.x, he = e >> 7;
    float u[NGRP], ag[NGRP];
    #pragma unroll
    for (int g = 0; g < NGRP; ++g) {
        u[g]  = Ugw[(((size_t)b*NGRP + g) << 8) + e];
        ag[g] = Agw[((size_t)b*NGRP + g)*2 + he];
    }
    float h = 0.f;
    #pragma unroll
    for (int g = 0; g < NGRP; ++g) {
        ghw[(((size_t)b*NGRP + g) << 8) + e] = h;
        h = fmaf(ag[g], h, u[g]);
    }
}

// K2b: consume staged tiles -> G, M~ (both heads), Y + hin correction, epilogue -> g2.
__global__ __launch_bounds__(256) void k2b_fused(
    const float* __restrict__ gtw,
    const float* __restrict__ ipw, const float* __restrict__ ipb,
    const float* __restrict__ Dv, const float* __restrict__ norm_w,
    const float* __restrict__ out_w, const float* __restrict__ out_b,
    const float* __restrict__ phw, const float* __restrict__ cpw,
    const float* __restrict__ ghw, const float* __restrict__ stw,
    float* __restrict__ g2w)
{
    __shared__ union {
        unsigned short Ct[64*40];     // C tile, K-pad zeroed
        float yb[64*20];              // y bounce (phase 3+)
    } uC;
    __shared__ __align__(16) unsigned short Bt[64*40];
    __shared__ __align__(16) unsigned short XTbf[16*72];
    __shared__ __align__(16) unsigned short M2[2][64*72];
    __shared__ __align__(16) unsigned short Cp0[64*16], Cp1[64*16];
    __shared__ __align__(16) unsigned short hinT[2][8*16];
    __shared__ float s_hin[256];
    __shared__ float s_la[128];
    __shared__ float s_eti[2][64], s_etd[2][64], s_esc[2][4][4];
    __shared__ float s_zw[128], s_ow[128], s_zb[16], s_nw[16], s_ob[8];

    int tid = threadIdx.x;
    int b = blockIdx.x >> 8, c = blockIdx.x & 255;
    const float* stp = stw + ((size_t)(b*NCH + c))*1792;
    const unsigned int* stX = (const unsigned int*)stp;
    const unsigned int* stB = (const unsigned int*)(stp + 512);
    const unsigned int* stC = (const unsigned int*)(stp + 1024);

    int r = tid >> 2, sub = tid & 3;
    float g0[8];
    load8(g0, gtw + ((size_t)b*LL + c*CHN + r)*GG);
    {   // hin reconstruction
        int grp = c >> 4;
        float gh  = ghw[(((size_t)b*NGRP + grp) << 8) + tid];
        float cpv = cpw[((size_t)b*NCH + c)*2 + (tid >> 7)];
        float phv = phw[(((size_t)b*NCH + c) << 8) + tid];
        s_hin[tid] = fmaf(cpv, gh, phv);
    }
    // tile copies -> LDS
    if (tid < 64) {
        int row = tid;
        *(uint4*)&uC.Ct[row*40]      = *(const uint4*)&stC[row*8];
        *(uint4*)&uC.Ct[row*40 + 8]  = *(const uint4*)&stC[row*8 + 4];
        *(uint4*)&uC.Ct[row*40 + 16] = make_uint4(0,0,0,0);
        *(uint4*)&uC.Ct[row*40 + 24] = make_uint4(0,0,0,0);
    } else if (tid < 128) {
        int row = tid - 64;
        *(uint4*)&Bt[row*40]      = *(const uint4*)&stB[row*8];
        *(uint4*)&Bt[row*40 + 8]  = *(const uint4*)&stB[row*8 + 4];
        *(uint4*)&Bt[row*40 + 16] = make_uint4(0,0,0,0);
        *(uint4*)&Bt[row*40 + 24] = make_uint4(0,0,0,0);
    } else {
        int i = tid - 128;
        int p = i >> 3, seg = i & 7;
        *(uint4*)&XTbf[p*72 + seg*8] = *(const uint4*)&stX[p*32 + seg*4];
    }
    if (tid < 128) { s_la[tid] = stp[1536 + tid]; s_zw[tid] = ipw[tid]; }
    else s_ow[tid-128] = out_w[tid-128];
    if (tid < 16) { s_zb[tid] = ipb[tid]; s_nw[tid] = norm_w[tid]; }
    else if (tid < 24) s_ob[tid-16] = out_b[tid-16];
    __syncthreads();                                      // B0

    float D0 = Dv[0], D1 = Dv[1];
    int lane = tid & 63, wv = tid >> 6;
    int ar = lane & 15, kb = lane >> 4;
    int trow = wv*16 + kb*4;

    // ---- phase 1: G-MFMAs, Cp, hinT, exp tables ----
    f32x4 gT[4];
    {
        bf16x8 aC = *(const bf16x8*)&uC.Ct[(wv*16 + ar)*40 + kb*8];
        #pragma unroll
        for (int ss = 0; ss < 4; ++ss) {
            f32x4 g = {0.f, 0.f, 0.f, 0.f};
            if (ss <= wv) {
                bf16x8 bB = *(const bf16x8*)&Bt[(ss*16 + ar)*40 + kb*8];
                g = __builtin_amdgcn_mfma_f32_16x16x32_bf16(aC, bB, g, 0, 0, 0);
            }
            gT[ss] = g;
        }
    }
    if (tid < 128) {   // Cp = exp(la)*C, both heads
        int h = tid >> 6;
        int rr = (tid & 63);
        float sc = __expf(s_la[rr*2 + h]);
        unsigned short* Cp = h ? Cp1 : Cp0;
        unsigned int* dst = (unsigned int*)&Cp[rr*16];
        #pragma unroll
        for (int j = 0; j < 8; ++j)
            dst[j] = pack2bf(sc * bf2f(uC.Ct[rr*40 + j*2]),
                             sc * bf2f(uC.Ct[rr*40 + j*2 + 1]));
        if (tid < 32) {   // hinT build
            int i = tid;
            int hh = i >> 4, p = (i >> 1) & 7, half = i & 1;
            unsigned int wd[4];
            #pragma unroll
            for (int j = 0; j < 4; ++j)
                wd[j] = pack2bf(s_hin[hh*128 + p*16 + half*8 + 2*j],
                                s_hin[hh*128 + p*16 + half*8 + 2*j + 1]);
            *(uint4*)&hinT[hh][p*16 + half*8] = make_uint4(wd[0],wd[1],wd[2],wd[3]);
        }
    } else {           // exp tables
        int i = tid - 128;
        int h = i >> 6, s = i & 63;
        int anc = s & ~15;
        float d = s_la[anc*2 + h] - s_la[s*2 + h];
        float dtv = stp[1664 + s*2 + h];
        s_eti[h][s] = __expf(-d);
        s_etd[h][s] = __expf(d) * dtv;
        if (i < 32) {
            int h2 = i >> 4, wt = (i >> 2) & 3, ws = i & 3;
            s_esc[h2][wt][ws] = (wt >= ws) ?
                __expf(s_la[(wt*16)*2 + h2] - s_la[(ws*16)*2 + h2]) : 0.f;
        }
    }
    __syncthreads();                                      // B1

    {   // ---- phase 2: M~ both heads (table-driven, trunc-pack dword stores) ----
        float rowf0[4], rowf1[4];
        #pragma unroll
        for (int rg = 0; rg < 4; ++rg) {
            rowf0[rg] = s_eti[0][trow+rg];
            rowf1[rg] = s_eti[1][trow+rg];
        }
        #pragma unroll
        for (int ss = 0; ss < 4; ++ss) {
            int s = ss*16 + ar;
            if (ss > wv) {
                if (!(ar & 1)) {
                    #pragma unroll
                    for (int rg = 0; rg < 4; ++rg) {
                        *(unsigned int*)&M2[0][(trow+rg)*72 + ss*16 + ar] = 0u;
                        *(unsigned int*)&M2[1][(trow+rg)*72 + ss*16 + ar] = 0u;
                    }
                }
                continue;
            }
            float colf0 = s_esc[0][wv][ss] * s_etd[0][s];
            float colf1 = s_esc[1][wv][ss] * s_etd[1][s];
            #pragma unroll
            for (int rg = 0; rg < 4; ++rg) {
                bool keep = (s <= trow+rg);
                float m0 = keep ? rowf0[rg]*colf0*gT[ss][rg] : 0.f;
                float m1 = keep ? rowf1[rg]*colf1*gT[ss][rg] : 0.f;
                float m0p = __shfl_xor(m0, 1);
                float m1p = __shfl_xor(m1, 1);
                if (!(ar & 1)) {
                    *(unsigned int*)&M2[0][(trow+rg)*72 + ss*16 + ar] = packtr(m0, m0p);
                    *(unsigned int*)&M2[1][(trow+rg)*72 + ss*16 + ar] = packtr(m1, m1p);
                }
            }
        }
    }
    __syncthreads();                                      // B2

    {   // ---- phase 3: Y = M~.X + Cp.hinT, both heads; yb store (overlays Ct) ----
        int p = ar;
        f32x4 acc0 = {0.f,0.f,0.f,0.f}, acc1 = {0.f,0.f,0.f,0.f};
        #pragma unroll
        for (int kk = 0; kk < 2; ++kk) {
            bf16x8 am0 = *(const bf16x8*)&M2[0][(wv*16 + ar)*72 + kk*32 + kb*8];
            bf16x8 am1 = *(const bf16x8*)&M2[1][(wv*16 + ar)*72 + kk*32 + kb*8];
            bf16x8 bx0 = {0,0,0,0,0,0,0,0}, bx1 = {0,0,0,0,0,0,0,0};
            if (p < 8) {
                bx0 = *(const bf16x8*)&XTbf[p*72 + kk*32 + kb*8];
                bx1 = *(const bf16x8*)&XTbf[(8+p)*72 + kk*32 + kb*8];
            }
            acc0 = __builtin_amdgcn_mfma_f32_16x16x32_bf16(am0, bx0, acc0, 0, 0, 0);
            acc1 = __builtin_amdgcn_mfma_f32_16x16x32_bf16(am1, bx1, acc1, 0, 0, 0);
        }
        bf16x8 aCp0 = {0,0,0,0,0,0,0,0}, aCp1 = {0,0,0,0,0,0,0,0};
        bf16x8 bh0 = {0,0,0,0,0,0,0,0}, bh1 = {0,0,0,0,0,0,0,0};
        if (kb < 2) {
            aCp0 = *(const bf16x8*)&Cp0[(wv*16 + ar)*16 + kb*8];
            aCp1 = *(const bf16x8*)&Cp1[(wv*16 + ar)*16 + kb*8];
            if (ar < 8) {
                bh0 = *(const bf16x8*)&hinT[0][ar*16 + kb*8];
                bh1 = *(const bf16x8*)&hinT[1][ar*16 + kb*8];
            }
        }
        acc0 = __builtin_amdgcn_mfma_f32_16x16x32_bf16(aCp0, bh0, acc0, 0, 0, 0);
        acc1 = __builtin_amdgcn_mfma_f32_16x16x32_bf16(aCp1, bh1, acc1, 0, 0, 0);
        if (p < 8) {
            #pragma unroll
            for (int rg = 0; rg < 4; ++rg) {
                int t = trow + rg;
                uC.yb[t*20 + p]     = fmaf(D0, bf2f(XTbf[p*72 + t]),     acc0[rg]);
                uC.yb[t*20 + 8 + p] = fmaf(D1, bf2f(XTbf[(8+p)*72 + t]), acc1[rg]);
            }
        }
    }
    __syncthreads();                                      // B3

    {   // ---- phase 4: epilogue ----
        int q = sub;
        float vv[4]; float ssq = 0.f;
        #pragma unroll
        for (int j = 0; j < 4; ++j) {
            int hp = q*4 + j;
            float zz = s_zb[hp];
            #pragma unroll
            for (int g = 0; g < 8; ++g) zz = fmaf(g0[g], s_zw[hp*8+g], zz);
            float y = uC.yb[r*20 + hp];
            float w = y * siluf(zz);
            vv[j] = w; ssq = fmaf(w, w, ssq);
        }
        ssq += __shfl_xor(ssq, 1);
        ssq += __shfl_xor(ssq, 2);
        float rn = rsqrtf(ssq*(1.f/16.f) + 1e-5f);
        float o[8];
        #pragma unroll
        for (int g = 0; g < 8; ++g) o[g] = 0.f;
        #pragma unroll
        for (int j = 0; j < 4; ++j) {
            float wj = vv[j] * rn * s_nw[q*4+j];
            #pragma unroll
            for (int g = 0; g < 8; ++g) o[g] = fmaf(wj, s_ow[g*16 + q*4 + j], o[g]);
        }
        #pragma unroll
        for (int g = 0; g < 8; ++g) {
            o[g] += __shfl_xor(o[g], 1);
            o[g] += __shfl_xor(o[g], 2);
        }
        if (q == 0) {
            #pragma unroll
            for (int g = 0; g < 8; ++g) o[g] += s_ob[g] + g0[g];
            float* gp = g2w + ((size_t)b*LL + c*CHN + r)*GG;
            ((float4*)gp)[0] = make_float4(o[0],o[1],o[2],o[3]);
            ((float4*)gp)[1] = make_float4(o[4],o[5],o[6],o[7]);
        }
    }
}

// K5b: out = x + detok(g2) + detok_b.
__global__ __launch_bounds__(64) void k5b_detok(
    const float* __restrict__ x, const float* __restrict__ g2w,
    const float* __restrict__ dkw, const float* __restrict__ dkb,
    float* __restrict__ outp)
{
    __shared__ float s_dw[CF*GG];
    __shared__ float s_db[CF];
    int tid = threadIdx.x;
    int b  = blockIdx.x >> 6;
    int ck = blockIdx.x & 63;
    int l0 = (ck << 8) + (tid << 2);
    for (int i = tid; i < CF*GG; i += 64) s_dw[i] = dkw[i];
    s_db[tid] = dkb[tid];
    __syncthreads();
    float g2v[4][8];
    const float* gp = g2w + ((size_t)b*LL + l0)*GG;
    #pragma unroll
    for (int r = 0; r < 4; ++r) load8(g2v[r], gp + r*GG);
    const float* xb = x + (size_t)b*CF*LL + l0;
    float* ob = outp + (size_t)b*CF*LL + l0;
    #pragma unroll 4
    for (int c = 0; c < CF; ++c) {
        float4 xv = *(const float4*)(xb + (size_t)c*LL);
        float bias = s_db[c];
        float oa[4] = {xv.x+bias, xv.y+bias, xv.z+bias, xv.w+bias};
        #pragma unroll
        for (int g = 0; g < GG; ++g) {
            float w = s_dw[c*GG+g];
            #pragma unroll
            for (int r = 0; r < 4; ++r) oa[r] = fmaf(g2v[r][g], w, oa[r]);
        }
        *(float4*)(ob + (size_t)c*LL) = make_float4(oa[0],oa[1],oa[2],oa[3]);
    }
}

extern "C" void kernel_launch(void* const* d_in, const int* in_sizes, int n_in,
                              void* d_out, int out_size, void* d_ws, size_t ws_size,
                              hipStream_t stream) {
    const float* x       = (const float*)d_in[0];
    const float* tok_w   = (const float*)d_in[1];
    const float* tok_b   = (const float*)d_in[2];
    const float* detok_w = (const float*)d_in[3];
    const float* detok_b = (const float*)d_in[4];
    const float* ipw     = (const float*)d_in[5];
    const float* ipb     = (const float*)d_in[6];
    const float* cw      = (const float*)d_in[7];
    const float* cb      = (const float*)d_in[8];
    const float* A_log   = (const float*)d_in[9];
    const float* Dv      = (const float*)d_in[10];
    const float* dt_bias = (const float*)d_in[11];
    const float* norm_w  = (const float*)d_in[12];
    const float* out_w   = (const float*)d_in[13];
    const float* out_b   = (const float*)d_in[14];
    float* ws = (float*)d_ws;
    float* outp = (float*)d_out;

    if (ws_size < WS_FLOATS * sizeof(float)) return;

    k1a_tok<<<NB*64, 64, 0, stream>>>(x, tok_w, tok_b, ws+OFF_GT);
    k2a_state<<<NB*NCH, 256, 0, stream>>>(ws+OFF_GT, ipw, ipb, cw, cb,
        A_log, dt_bias, ws+OFF_ST, ws+OFF_U2, ws+OFF_AC);
    k4c1<<<NB*NGRP, 256, 0, stream>>>(ws+OFF_U2, ws+OFF_AC,
        ws+OFF_PH, ws+OFF_CP, ws+OFF_UG, ws+OFF_AG);
    k4c2<<<NB, 256, 0, stream>>>(ws+OFF_UG, ws+OFF_AG, ws+OFF_GH);
    k2b_fused<<<NB*NCH, 256, 0, stream>>>(ws+OFF_GT, ipw, ipb,
        Dv, norm_w, out_w, out_b,
        ws+OFF_PH, ws+OFF_CP, ws+OFF_GH, ws+OFF_ST, ws+OFF_G2);
    k5b_detok<<<NB*64, 64, 0, stream>>>(x, ws+OFF_G2, detok_w, detok_b, outp);
}